// Round 6
// baseline (537.314 us; speedup 1.0000x reference)
//
#include <hip/hip_runtime.h>
#include <hip/hip_fp16.h>
#include <math.h>

#define TSZ2 4096
#define RMAXF 2.0f
#define NBAS 10
#define HID 100
#define SCB 1024   // scan elements per block
#define CHK 4096   // edges per binning block

__device__ __forceinline__ float sigmoidf_(float z) { return 1.0f / (1.0f + __expf(-z)); }
__device__ __forceinline__ float2 unp_h2(unsigned u) {
    __half2 h = __builtin_bit_cast(__half2, u);
    return __half22float2(h);
}
__device__ __forceinline__ unsigned pk_h2(float a, float b) {
    return __builtin_bit_cast(unsigned, __floats2half2_rn(a, b));
}

// ---------------- radial table (fp32, [l][t][48]), 32 t-values per block ----------------
__global__ void k_table(const float* __restrict__ w1, const float* __restrict__ b1,
                        const float* __restrict__ w2, float* __restrict__ wtab) {
    int l = blockIdx.x >> 7;
    int t0 = (blockIdx.x & 127) * 32;
    __shared__ float emb[32][NBAS];
    __shared__ float h[32][HID];
    __shared__ float w2s[HID * 48];
    int tid = threadIdx.x;
    for (int i = tid; i < HID * 48; i += 256) w2s[i] = w2[l * HID * 48 + i];
    for (int i = tid; i < 32 * NBAS; i += 256) {
        int tt = i / NBAS, bi = i % NBAS;
        float r = (16.0f * (t0 + tt) + 7.5f) * (RMAXF / 65535.0f);
        float d = (r - (bi + 0.5f) * 0.2f) * 5.0f;
        emb[tt][bi] = (fabsf(d) < 1.0f) ? cosf(1.5707963267948966f * d) * 3.1622776601683795f : 0.0f;
    }
    __syncthreads();
    for (int i = tid; i < 32 * HID; i += 256) {
        int tt = i / HID, hh = i % HID;
        float z = b1[l * HID + hh];
        #pragma unroll
        for (int bi = 0; bi < NBAS; ++bi) z += emb[tt][bi] * w1[(l * NBAS + bi) * HID + hh];
        h[tt][hh] = z * sigmoidf_(z);
    }
    __syncthreads();
    for (int i = tid; i < 32 * 48; i += 256) {
        int tt = i / 48, j = i % 48;
        float o = 0.0f;
        for (int k = 0; k < HID; ++k) o += h[tt][k] * w2s[k * 48 + j];
        wtab[((size_t)l * TSZ2 + t0 + tt) * 48 + j] = o;
    }
}

// ---------------- pack table: [l][t][p] uint4 {h2(w0a,w1a), h2(w2a,w0b), h2(w1b,w2b), 0}
__global__ void k_pack(const float* __restrict__ wtab, uint4* __restrict__ tp) {
    int idx = blockIdx.x * blockDim.x + threadIdx.x;
    if (idx >= 3 * TSZ2 * 8) return;
    int p = idx & 7;
    int t = (idx >> 3) & (TSZ2 - 1);
    int l = idx >> 15;
    uint4 o = make_uint4(0, 0, 0, 0);
    if (t != TSZ2 - 1) {  // last row = sentinel zeros
        const float* wt = wtab + ((size_t)l * TSZ2 + t) * 48;
        o.x = pk_h2(wt[2 * p], wt[16 + 2 * p]);
        o.y = pk_h2(wt[32 + 2 * p], wt[2 * p + 1]);
        o.z = pk_h2(wt[17 + 2 * p], wt[33 + 2 * p]);
    }
    tp[idx] = o;
}

// ---------------- histogram: per-node (global atomics) + per-bucket (LDS-agg) ----------------
__global__ void k_hist(const int* __restrict__ edst, int* cnt, int* bhist, int E) {
    __shared__ int lb[512];
    int tid = threadIdx.x;
    for (int i = tid; i < 512; i += 256) lb[i] = 0;
    __syncthreads();
    int e0 = blockIdx.x * CHK;
    #pragma unroll
    for (int k = 0; k < CHK / 256; ++k) {
        int e = e0 + k * 256 + tid;
        if (e < E) {
            int d = edst[e];
            atomicAdd(&cnt[d], 1);
            atomicAdd(&lb[d >> 7], 1);
        }
    }
    __syncthreads();
    for (int i = tid; i < 512; i += 256) if (lb[i]) atomicAdd(&bhist[i], lb[i]);
}

// ---------------- bucket scan (1 block, 512 threads) ----------------
__global__ void k_bscan(const int* __restrict__ bhist, int* __restrict__ bbase,
                        int* __restrict__ bcursor, int nbuck, int E) {
    __shared__ int part[512];
    int t = threadIdx.x;
    part[t] = (t < nbuck) ? bhist[t] : 0;
    __syncthreads();
    for (int off = 1; off < 512; off <<= 1) {
        int v = (t >= off) ? part[t - off] : 0;
        __syncthreads();
        part[t] += v;
        __syncthreads();
    }
    int ex = (t == 0) ? 0 : part[t - 1];
    if (t < nbuck) { bbase[t] = ex; bcursor[t] = ex; }
    if (t == 0) bbase[nbuck] = E;
}

// ---------------- node-level scans (padded to 8) ----------------
__global__ void k_scanA(const int* __restrict__ cnt, int* __restrict__ bsum, int N) {
    __shared__ int red[256];
    int base = blockIdx.x * SCB;
    int t = threadIdx.x;
    int s = 0;
    #pragma unroll
    for (int k = 0; k < 4; ++k) {
        int i = base + k * 256 + t;
        if (i < N) s += (cnt[i] + 7) & ~7;
    }
    red[t] = s;
    __syncthreads();
    for (int off = 128; off > 0; off >>= 1) {
        if (t < off) red[t] += red[t + off];
        __syncthreads();
    }
    if (t == 0) bsum[blockIdx.x] = red[0];
}

__global__ void k_scanB(const int* __restrict__ bsum, int* __restrict__ boff, int nb) {
    __shared__ int part[256];
    int t = threadIdx.x;
    part[t] = (t < nb) ? bsum[t] : 0;
    __syncthreads();
    for (int off = 1; off < 256; off <<= 1) {
        int v = (t >= off) ? part[t - off] : 0;
        __syncthreads();
        part[t] += v;
        __syncthreads();
    }
    boff[t] = (t == 0) ? 0 : part[t - 1];
}

__global__ void k_scanC(const int* __restrict__ cnt, const int* __restrict__ boff,
                        int* __restrict__ row_start, int* __restrict__ cursor, int N) {
    __shared__ int part[256];
    int b = blockIdx.x, t = threadIdx.x;
    int base = b * SCB;
    int v[4];
    int s = 0;
    #pragma unroll
    for (int k = 0; k < 4; ++k) {
        int i = base + t * 4 + k;
        v[k] = (i < N) ? ((cnt[i] + 7) & ~7) : 0;
        s += v[k];
    }
    part[t] = s;
    __syncthreads();
    for (int off = 1; off < 256; off <<= 1) {
        int x = (t >= off) ? part[t - off] : 0;
        __syncthreads();
        part[t] += x;
        __syncthreads();
    }
    int run = boff[b] + ((t == 0) ? 0 : part[t - 1]);
    #pragma unroll
    for (int k = 0; k < 4; ++k) {
        int i = base + t * 4 + k;
        if (i < N) {
            row_start[i] = run; cursor[i] = run; run += v[k];
            if (i == N - 1) row_start[N] = run;
        }
    }
}

// ---------------- phase 1: bin edges into dst-buckets with geometry, burst writes ----------------
__global__ void k_scat1(const float* __restrict__ pos, const int* __restrict__ esrc,
                        const int* __restrict__ edst, int* __restrict__ bcursor,
                        uint4* __restrict__ bbuf, int E, int nbuck) {
    __shared__ int lcnt[512];
    __shared__ int base[512];
    int tid = threadIdx.x;
    for (int i = tid; i < 512; i += 256) lcnt[i] = 0;
    __syncthreads();
    int e0 = blockIdx.x * CHK;
    #pragma unroll
    for (int k = 0; k < CHK / 256; ++k) {
        int e = e0 + k * 256 + tid;
        if (e < E) atomicAdd(&lcnt[edst[e] >> 7], 1);
    }
    __syncthreads();
    for (int b = tid; b < nbuck; b += 256)
        base[b] = lcnt[b] ? atomicAdd(&bcursor[b], lcnt[b]) : 0;
    __syncthreads();
    #pragma unroll
    for (int k = 0; k < CHK / 256; ++k) {
        int e = e0 + k * 256 + tid;
        if (e >= E) continue;
        int s = esrc[e], d = edst[e];
        float vx = pos[s * 3 + 0] - pos[d * 3 + 0];
        float vy = pos[s * 3 + 1] - pos[d * 3 + 1];
        float vz = pos[s * 3 + 2] - pos[d * 3 + 2];
        float r = sqrtf(vx * vx + vy * vy + vz * vz);
        float kf = 1.7320508075688772f / (r + 1e-12f);   // sqrt(3)/r premult
        unsigned rtfix = (unsigned)fminf(r * (65535.0f / RMAXF) + 0.5f, 65535.0f);
        uint4 o;
        o.x = (unsigned)s | (rtfix << 16);
        o.y = pk_h2(vx * kf, vy * kf);
        o.z = __float_as_uint(vz * kf);
        o.w = (unsigned)d;
        int slot = atomicAdd(&base[d >> 7], 1);
        bbuf[slot] = o;
    }
}

// ---------------- phase 2: bucket -> exact CSR slot (L2-resident region per block) ----------------
__global__ void k_scat2(const uint4* __restrict__ bbuf, const int* __restrict__ bbase,
                        int* __restrict__ cursor, uint4* __restrict__ csr) {
    int b = blockIdx.x;
    int j0 = bbase[b], j1 = bbase[b + 1];
    for (int j = j0 + threadIdx.x; j < j1; j += 256) {
        uint4 e = bbuf[j];
        int d = (int)e.w;
        int slot = atomicAdd(&cursor[d], 1);
        csr[slot] = e;
    }
}

// ---------------- fill pad slots with sentinel edges ----------------
__global__ void k_padfill(const int* __restrict__ cursor, const int* __restrict__ row_start,
                          uint4* __restrict__ csr, int N) {
    int n = blockIdx.x * blockDim.x + threadIdx.x;
    if (n >= N) return;
    int s0 = cursor[n], s1 = row_start[n + 1];
    uint4 sent = make_uint4(0xFFFF0000u, 0, 0, 0);
    for (int s = s0; s < s1; ++s) csr[s] = sent;
}

// ---------------- p0 = x0 @ P0[l] ----------------
__global__ void k_p0(const float* __restrict__ x0, const float* __restrict__ P0l,
                     float* __restrict__ p0, int N) {
    int i = blockIdx.x * blockDim.x + threadIdx.x;
    if (i >= N * 16) return;
    int n = i >> 4, m = i & 15;
    float acc = 0.0f;
    #pragma unroll
    for (int c = 0; c < 16; ++c) acc += x0[n * 16 + c] * P0l[c * 16 + m];
    p0[i] = acc;
}

// ---------------- fused aggregation + node update; 8-lane group per node, 8 nodes/wave ----------------
__launch_bounds__(256)
__global__ void k_aggupd(const int* __restrict__ row_start, const uint4* __restrict__ csr,
                         const uint4* __restrict__ tbp, const float* __restrict__ p0g,
                         const float* __restrict__ x0c, const float* __restrict__ x1c,
                         const float* __restrict__ x2c,
                         float* __restrict__ x0n, float* __restrict__ x1n, float* __restrict__ x2n,
                         const float* __restrict__ Wsc, const float* __restrict__ Wa,
                         const float* __restrict__ W1m, const float* __restrict__ W2m,
                         int N, int ldx12) {
    const float INVS = 0.17677669529663687f;  // 1/sqrt(32)
    const float K1  = 1.2909944487358056f;    // sqrt(15)/3
    const float S5H = 1.118033988749895f;     // sqrt(5)/2
    const float K2  = 0.6454972243679028f;    // sqrt(15)/2/3
    __shared__ float AGG[32][144];
    int tid = threadIdx.x;
    int wid = tid >> 6;
    int lane = tid & 63;
    int g = lane >> 3, p = lane & 7;    // node group, channel pair
    int n = blockIdx.x * 32 + wid * 8 + g;
    int e0 = 0, plen = 0;
    if (n < N) { e0 = row_start[n]; plen = row_start[n + 1] - e0; }
    int maxlen = plen;
    maxlen = max(maxlen, __shfl_xor(maxlen, 8));
    maxlen = max(maxlen, __shfl_xor(maxlen, 16));
    maxlen = max(maxlen, __shfl_xor(maxlen, 32));
    float A0[2] = {0, 0};
    float A1[2][3] = {};
    float A2[2][5] = {};
    if (maxlen > 0) {
        const float2* p0f2 = (const float2*)p0g;
        auto LOADC = [&](int k) -> uint4 { return csr[e0 + (k < plen ? k : 0)]; };
        auto TIDX  = [&](int k, unsigned cx) -> unsigned { return (k < plen) ? (cx >> 20) : 4095u; };
        uint4 ca = LOADC(0);
        uint4 cb = LOADC(1);
        uint4 cc_ = LOADC(2);
        float2 Pa = p0f2[(ca.x & 0xffffu) * 8 + p];
        uint4  Ta = tbp[TIDX(0, ca.x) * 8 + p];
        float2 Pb = p0f2[(cb.x & 0xffffu) * 8 + p];
        uint4  Tb = tbp[TIDX(1, cb.x) * 8 + p];
        for (int k = 0; k < maxlen; ++k) {
            uint4 cn = LOADC(k + 3);
            float2 Pn = p0f2[(cc_.x & 0xffffu) * 8 + p];
            uint4  Tn = tbp[TIDX(k + 2, cc_.x) * 8 + p];
            // ---- compute edge k (weights zero for sentinel/overrun -> contribution zero) ----
            float2 uxy = unp_h2(ca.y);
            float ux = uxy.x, uy = uxy.y, uz = __uint_as_float(ca.z);
            float sh20 = K1 * (ux * uy);
            float sh21 = K1 * (uy * uz);
            float sh22 = S5H * (uz * uz - 1.0f);
            float sh23 = K1 * (ux * uz);
            float sh24 = K2 * (ux * ux - uy * uy);
            float2 q0 = unp_h2(Ta.x);   // w0a, w1a
            float2 q1 = unp_h2(Ta.y);   // w2a, w0b
            float2 q2 = unp_h2(Ta.z);   // w1b, w2b
            A0[0] += q0.x * Pa.x;
            float w1a = q0.y * Pa.x, w2a = q1.x * Pa.x;
            A1[0][0] += w1a * ux; A1[0][1] += w1a * uy; A1[0][2] += w1a * uz;
            A2[0][0] += w2a * sh20; A2[0][1] += w2a * sh21; A2[0][2] += w2a * sh22;
            A2[0][3] += w2a * sh23; A2[0][4] += w2a * sh24;
            A0[1] += q1.y * Pa.y;
            float w1b = q2.x * Pa.y, w2b = q2.y * Pa.y;
            A1[1][0] += w1b * ux; A1[1][1] += w1b * uy; A1[1][2] += w1b * uz;
            A2[1][0] += w2b * sh20; A2[1][1] += w2b * sh21; A2[1][2] += w2b * sh22;
            A2[1][3] += w2b * sh23; A2[1][4] += w2b * sh24;
            // rotate pipeline
            ca = cb; Pa = Pb; Ta = Tb;
            cb = cc_; Pb = Pn; Tb = Tn;
            cc_ = cn;
        }
    }
    {
        float* Ag = AGG[wid * 8 + g];
        int c = 2 * p;
        Ag[c]     = A0[0] * INVS;
        Ag[c + 1] = A0[1] * INVS;
        #pragma unroll
        for (int d = 0; d < 3; ++d) {
            Ag[16 + c * 3 + d]       = A1[0][d] * INVS;
            Ag[16 + (c + 1) * 3 + d] = A1[1][d] * INVS;
        }
        #pragma unroll
        for (int d = 0; d < 5; ++d) {
            Ag[64 + c * 5 + d]       = A2[0][d] * INVS;
            Ag[64 + (c + 1) * 5 + d] = A2[1][d] * INVS;
        }
    }
    __syncthreads();
    // ---- tail: node update, 8 nodes per wave (serial q) ----
    for (int q = 0; q < 8; ++q) {
        int nn = blockIdx.x * 32 + wid * 8 + q;
        if (nn >= N) continue;
        const float* A = AGG[wid * 8 + q];
        float act = 0.0f;
        if (lane < 48) {
            float sj = 0.0f;
            #pragma unroll
            for (int cc = 0; cc < 16; ++cc)
                sj += x0c[nn * 16 + cc] * Wsc[cc * 48 + lane] + A[cc] * Wa[cc * 48 + lane];
            float sg = sigmoidf_(sj);
            act = (lane < 16) ? sj * sg : sg;
        }
        if (lane < 16) x0n[nn * 16 + lane] = act;
        {
            int d = lane >> 4, m = lane & 15;
            float v = 0.0f;
            if (lane < 48) {
                if (ldx12) {
                    #pragma unroll
                    for (int cc = 0; cc < 16; ++cc) v += x1c[(size_t)nn * 48 + cc * 3 + d] * W1m[cc * 16 + m];
                }
                v += A[16 + m * 3 + d];
            }
            float sg1 = __shfl(act, 16 + m);
            if (lane < 48) x1n[(size_t)nn * 48 + m * 3 + d] = v * sg1;
        }
        #pragma unroll
        for (int ch = 0; ch < 2; ++ch) {
            int idx = ch * 64 + lane;
            int d = idx >> 4, m = idx & 15;
            bool on = idx < 80;
            float v = 0.0f;
            if (on) {
                if (ldx12) {
                    #pragma unroll
                    for (int cc = 0; cc < 16; ++cc) v += x2c[(size_t)nn * 80 + cc * 5 + d] * W2m[cc * 16 + m];
                }
                v += A[64 + m * 5 + d];
            }
            float sg2 = __shfl(act, 32 + (m & 15));
            if (on) x2n[(size_t)nn * 80 + m * 5 + d] = v * sg2;
        }
    }
}

// ---------------- final reduction ----------------
__global__ void k_out1(const float* __restrict__ x0, const float* __restrict__ Wout,
                       float* __restrict__ partial, int N) {
    __shared__ float red[256];
    int tid = threadIdx.x;
    float s = 0.0f;
    for (int n = blockIdx.x * blockDim.x + tid; n < N; n += gridDim.x * blockDim.x) {
        float acc = 0.0f;
        #pragma unroll
        for (int cc = 0; cc < 16; ++cc) acc += x0[n * 16 + cc] * Wout[cc];
        s += acc;
    }
    red[tid] = s;
    __syncthreads();
    for (int off = 128; off > 0; off >>= 1) {
        if (tid < off) red[tid] += red[tid + off];
        __syncthreads();
    }
    if (tid == 0) partial[blockIdx.x] = red[0];
}

__global__ void k_out2(const float* __restrict__ partial, float* __restrict__ out,
                       int nb, float scale) {
    __shared__ float red[256];
    int tid = threadIdx.x;
    red[tid] = (tid < nb) ? partial[tid] : 0.0f;
    __syncthreads();
    for (int off = 128; off > 0; off >>= 1) {
        if (tid < off) red[tid] += red[tid + off];
        __syncthreads();
    }
    if (tid == 0) out[0] = red[0] * scale;
}

extern "C" void kernel_launch(void* const* d_in, const int* in_sizes, int n_in,
                              void* d_out, int out_size, void* d_ws, size_t ws_size,
                              hipStream_t stream) {
    const float* pos = (const float*)d_in[0];
    const float* x   = (const float*)d_in[1];
    const int* esrc  = (const int*)d_in[2];
    const int* edst  = (const int*)d_in[3];
    const float* mlp_w1 = (const float*)d_in[5];
    const float* mlp_b1 = (const float*)d_in[6];
    const float* mlp_w2 = (const float*)d_in[7];
    const float* P0  = (const float*)d_in[8];
    const float* Wsc = (const float*)d_in[9];
    const float* Wa  = (const float*)d_in[10];
    const float* W1m = (const float*)d_in[11];
    const float* W2m = (const float*)d_in[12];
    const float* Wout = (const float*)d_in[13];
    int N = in_sizes[0] / 3;
    int E = in_sizes[2];
    int cap = E + 8 * N + 64;
    int nbuck = (N + 127) >> 7;          // dst >> 7 buckets (<= 512)

    char* ws = (char*)d_ws;
    size_t off = 0;
    auto alloc = [&](size_t bytes) -> void* {
        void* p = ws + off;
        off += (bytes + 255) & ~(size_t)255;
        return p;
    };
    int*    cnt       = (int*)alloc((size_t)N * 4);
    int*    row_start = (int*)alloc((size_t)(N + 1) * 4);
    int*    cursor    = (int*)alloc((size_t)N * 4);
    int*    bsum      = (int*)alloc(256 * 4);
    int*    boff      = (int*)alloc(256 * 4);
    int*    bhist     = (int*)alloc(512 * 4);
    int*    bbase     = (int*)alloc(513 * 4);
    int*    bcursor   = (int*)alloc(512 * 4);
    uint4*  csr       = (uint4*)alloc((size_t)cap * 16);
    float*  wtab      = (float*)alloc((size_t)3 * TSZ2 * 48 * 4);
    uint4*  tbp       = (uint4*)alloc((size_t)3 * TSZ2 * 8 * 16);
    float*  p0  = (float*)alloc((size_t)65536 * 16 * 4);  // oversized: src is 16-bit
    float*  x0A = (float*)alloc((size_t)N * 16 * 4);
    float*  x0B = (float*)alloc((size_t)N * 16 * 4);
    float*  x1B = (float*)alloc((size_t)N * 48 * 4);
    float*  x2B = (float*)alloc((size_t)N * 80 * 4);
    // union region: bbuf (setup-only) aliases x1A + x2A (first written in layer 1)
    size_t x1Asz = ((size_t)N * 48 * 4 + 255) & ~(size_t)255;
    size_t unionSz = x1Asz + (size_t)N * 80 * 4;
    size_t bbufSz = (size_t)E * 16;
    char*  unionA = (char*)alloc(unionSz > bbufSz ? unionSz : bbufSz);
    float* x1A = (float*)unionA;
    float* x2A = (float*)(unionA + x1Asz);
    uint4* bbuf = (uint4*)unionA;
    float*  partial = (float*)alloc(256 * 4);

    int nbscan = (N + SCB - 1) / SCB;
    int nchunk = (E + CHK - 1) / CHK;

    hipMemsetAsync(cnt, 0, (size_t)N * 4, stream);
    hipMemsetAsync(bhist, 0, 512 * 4, stream);
    k_table<<<3 * (TSZ2 / 32), 256, 0, stream>>>(mlp_w1, mlp_b1, mlp_w2, wtab);
    k_pack<<<(3 * TSZ2 * 8 + 255) / 256, 256, 0, stream>>>(wtab, tbp);
    k_hist<<<nchunk, 256, 0, stream>>>(edst, cnt, bhist, E);
    k_scanA<<<nbscan, 256, 0, stream>>>(cnt, bsum, N);
    k_scanB<<<1, 256, 0, stream>>>(bsum, boff, nbscan);
    k_scanC<<<nbscan, 256, 0, stream>>>(cnt, boff, row_start, cursor, N);
    k_bscan<<<1, 512, 0, stream>>>(bhist, bbase, bcursor, nbuck, E);
    k_scat1<<<nchunk, 256, 0, stream>>>(pos, esrc, edst, bcursor, bbuf, E, nbuck);
    k_scat2<<<nbuck, 256, 0, stream>>>(bbuf, bbase, cursor, csr);
    k_padfill<<<(N + 255) / 256, 256, 0, stream>>>(cursor, row_start, csr, N);

    float* x0bufs[2] = {x0A, x0B};
    float* x1bufs[2] = {x1A, x1B};
    float* x2bufs[2] = {x2A, x2B};
    for (int l = 0; l < 3; ++l) {
        const float* x0c = (l == 0) ? x : x0bufs[l & 1];
        const float* x1c = x1bufs[l & 1];
        const float* x2c = x2bufs[l & 1];
        float* x0n = x0bufs[(l & 1) ^ 1];
        float* x1n = x1bufs[(l & 1) ^ 1];
        float* x2n = x2bufs[(l & 1) ^ 1];
        k_p0<<<(N * 16 + 255) / 256, 256, 0, stream>>>(x0c, P0 + l * 256, p0, N);
        k_aggupd<<<(N + 31) / 32, 256, 0, stream>>>(row_start, csr, tbp + (size_t)l * TSZ2 * 8, p0,
                                                    x0c, x1c, x2c, x0n, x1n, x2n,
                                                    Wsc + l * 768, Wa + l * 768,
                                                    W1m + l * 256, W2m + l * 256, N,
                                                    (l == 0) ? 0 : 1);
    }
    float scale = (float)(1.0 / sqrt((double)N));
    k_out1<<<256, 256, 0, stream>>>(x0bufs[1], Wout, partial, N);
    k_out2<<<1, 256, 0, stream>>>(partial, (float*)d_out, 256, scale);
}

// Round 7
// 409.382 us; speedup vs baseline: 1.3125x; 1.3125x over previous
//
#include <hip/hip_runtime.h>
#include <hip/hip_fp16.h>
#include <math.h>

#define TSZ2 4096
#define RMAXF 2.0f
#define NBAS 10
#define HID 100
#define SCB 1024   // scan elements per block
#define CHK 4096   // edges per binning block

__device__ __forceinline__ float sigmoidf_(float z) { return 1.0f / (1.0f + __expf(-z)); }
__device__ __forceinline__ float2 unp_h2(unsigned u) {
    __half2 h = __builtin_bit_cast(__half2, u);
    return __half22float2(h);
}
__device__ __forceinline__ unsigned pk_h2(float a, float b) {
    return __builtin_bit_cast(unsigned, __floats2half2_rn(a, b));
}

// ---------------- radial table (fp32, [l][t][48]), 32 t-values per block ----------------
__global__ void k_table(const float* __restrict__ w1, const float* __restrict__ b1,
                        const float* __restrict__ w2, float* __restrict__ wtab) {
    int l = blockIdx.x >> 7;
    int t0 = (blockIdx.x & 127) * 32;
    __shared__ float emb[32][NBAS];
    __shared__ float h[32][HID];
    __shared__ float w2s[HID * 48];
    int tid = threadIdx.x;
    for (int i = tid; i < HID * 48; i += 256) w2s[i] = w2[l * HID * 48 + i];
    for (int i = tid; i < 32 * NBAS; i += 256) {
        int tt = i / NBAS, bi = i % NBAS;
        float r = (16.0f * (t0 + tt) + 7.5f) * (RMAXF / 65535.0f);
        float d = (r - (bi + 0.5f) * 0.2f) * 5.0f;
        emb[tt][bi] = (fabsf(d) < 1.0f) ? cosf(1.5707963267948966f * d) * 3.1622776601683795f : 0.0f;
    }
    __syncthreads();
    for (int i = tid; i < 32 * HID; i += 256) {
        int tt = i / HID, hh = i % HID;
        float z = b1[l * HID + hh];
        #pragma unroll
        for (int bi = 0; bi < NBAS; ++bi) z += emb[tt][bi] * w1[(l * NBAS + bi) * HID + hh];
        h[tt][hh] = z * sigmoidf_(z);
    }
    __syncthreads();
    for (int i = tid; i < 32 * 48; i += 256) {
        int tt = i / 48, j = i % 48;
        float o = 0.0f;
        for (int k = 0; k < HID; ++k) o += h[tt][k] * w2s[k * 48 + j];
        wtab[((size_t)l * TSZ2 + t0 + tt) * 48 + j] = o;
    }
}

// ---------------- pack table: [l][t][c] uint2 {h2(w0,w1), h2(w2,0)} ----------------
__global__ void k_pack(const float* __restrict__ wtab, uint2* __restrict__ tp) {
    int idx = blockIdx.x * blockDim.x + threadIdx.x;
    if (idx >= 3 * TSZ2 * 16) return;
    int c = idx & 15;
    int t = (idx >> 4) & (TSZ2 - 1);
    int l = idx >> 16;
    uint2 o = make_uint2(0, 0);
    if (t != TSZ2 - 1) {  // last row = sentinel zeros
        const float* wt = wtab + ((size_t)l * TSZ2 + t) * 48;
        o.x = pk_h2(wt[c], wt[16 + c]);
        o.y = pk_h2(wt[32 + c], 0.0f);
    }
    tp[idx] = o;
}

// ---------------- histogram: per-node (global atomics) + per-bucket (LDS-agg) ----------------
__global__ void k_hist(const int* __restrict__ edst, int* cnt, int* bhist, int E) {
    __shared__ int lb[512];
    int tid = threadIdx.x;
    for (int i = tid; i < 512; i += 256) lb[i] = 0;
    __syncthreads();
    int e0 = blockIdx.x * CHK;
    #pragma unroll
    for (int k = 0; k < CHK / 256; ++k) {
        int e = e0 + k * 256 + tid;
        if (e < E) {
            int d = edst[e];
            atomicAdd(&cnt[d], 1);
            atomicAdd(&lb[d >> 7], 1);
        }
    }
    __syncthreads();
    for (int i = tid; i < 512; i += 256) if (lb[i]) atomicAdd(&bhist[i], lb[i]);
}

// ---------------- bucket scan (1 block, 512 threads) ----------------
__global__ void k_bscan(const int* __restrict__ bhist, int* __restrict__ bbase,
                        int* __restrict__ bcursor, int nbuck, int E) {
    __shared__ int part[512];
    int t = threadIdx.x;
    part[t] = (t < nbuck) ? bhist[t] : 0;
    __syncthreads();
    for (int off = 1; off < 512; off <<= 1) {
        int v = (t >= off) ? part[t - off] : 0;
        __syncthreads();
        part[t] += v;
        __syncthreads();
    }
    int ex = (t == 0) ? 0 : part[t - 1];
    if (t < nbuck) { bbase[t] = ex; bcursor[t] = ex; }
    if (t == 0) bbase[nbuck] = E;
}

// ---------------- node-level scans (padded to 8) ----------------
__global__ void k_scanA(const int* __restrict__ cnt, int* __restrict__ bsum, int N) {
    __shared__ int red[256];
    int base = blockIdx.x * SCB;
    int t = threadIdx.x;
    int s = 0;
    #pragma unroll
    for (int k = 0; k < 4; ++k) {
        int i = base + k * 256 + t;
        if (i < N) s += (cnt[i] + 7) & ~7;
    }
    red[t] = s;
    __syncthreads();
    for (int off = 128; off > 0; off >>= 1) {
        if (t < off) red[t] += red[t + off];
        __syncthreads();
    }
    if (t == 0) bsum[blockIdx.x] = red[0];
}

__global__ void k_scanB(const int* __restrict__ bsum, int* __restrict__ boff, int nb) {
    __shared__ int part[256];
    int t = threadIdx.x;
    part[t] = (t < nb) ? bsum[t] : 0;
    __syncthreads();
    for (int off = 1; off < 256; off <<= 1) {
        int v = (t >= off) ? part[t - off] : 0;
        __syncthreads();
        part[t] += v;
        __syncthreads();
    }
    boff[t] = (t == 0) ? 0 : part[t - 1];
}

__global__ void k_scanC(const int* __restrict__ cnt, const int* __restrict__ boff,
                        int* __restrict__ row_start, int* __restrict__ cursor, int N) {
    __shared__ int part[256];
    int b = blockIdx.x, t = threadIdx.x;
    int base = b * SCB;
    int v[4];
    int s = 0;
    #pragma unroll
    for (int k = 0; k < 4; ++k) {
        int i = base + t * 4 + k;
        v[k] = (i < N) ? ((cnt[i] + 7) & ~7) : 0;
        s += v[k];
    }
    part[t] = s;
    __syncthreads();
    for (int off = 1; off < 256; off <<= 1) {
        int x = (t >= off) ? part[t - off] : 0;
        __syncthreads();
        part[t] += x;
        __syncthreads();
    }
    int run = boff[b] + ((t == 0) ? 0 : part[t - 1]);
    #pragma unroll
    for (int k = 0; k < 4; ++k) {
        int i = base + t * 4 + k;
        if (i < N) {
            row_start[i] = run; cursor[i] = run; run += v[k];
            if (i == N - 1) row_start[N] = run;
        }
    }
}

// ---------------- phase 1: bin edges into dst-buckets with geometry, burst writes ----------------
__global__ void k_scat1(const float* __restrict__ pos, const int* __restrict__ esrc,
                        const int* __restrict__ edst, int* __restrict__ bcursor,
                        uint4* __restrict__ bbuf, int E, int nbuck) {
    __shared__ int lcnt[512];
    __shared__ int base[512];
    int tid = threadIdx.x;
    for (int i = tid; i < 512; i += 256) lcnt[i] = 0;
    __syncthreads();
    int e0 = blockIdx.x * CHK;
    #pragma unroll
    for (int k = 0; k < CHK / 256; ++k) {
        int e = e0 + k * 256 + tid;
        if (e < E) atomicAdd(&lcnt[edst[e] >> 7], 1);
    }
    __syncthreads();
    for (int b = tid; b < nbuck; b += 256)
        base[b] = lcnt[b] ? atomicAdd(&bcursor[b], lcnt[b]) : 0;
    __syncthreads();
    #pragma unroll
    for (int k = 0; k < CHK / 256; ++k) {
        int e = e0 + k * 256 + tid;
        if (e >= E) continue;
        int s = esrc[e], d = edst[e];
        float vx = pos[s * 3 + 0] - pos[d * 3 + 0];
        float vy = pos[s * 3 + 1] - pos[d * 3 + 1];
        float vz = pos[s * 3 + 2] - pos[d * 3 + 2];
        float r = sqrtf(vx * vx + vy * vy + vz * vz);
        float kf = 1.7320508075688772f / (r + 1e-12f);   // sqrt(3)/r premult
        unsigned rtfix = (unsigned)fminf(r * (65535.0f / RMAXF) + 0.5f, 65535.0f);
        uint4 o;
        o.x = (unsigned)s | (rtfix << 16);
        o.y = pk_h2(vx * kf, vy * kf);
        o.z = __float_as_uint(vz * kf);
        o.w = (unsigned)d;
        int slot = atomicAdd(&base[d >> 7], 1);
        bbuf[slot] = o;
    }
}

// ---------------- phase 2: bucket -> exact CSR slot + sentinel padfill (fused) ----------------
__global__ void k_scat2(const uint4* __restrict__ bbuf, const int* __restrict__ bbase,
                        int* __restrict__ cursor, const int* __restrict__ row_start,
                        uint4* __restrict__ csr, int N) {
    int b = blockIdx.x;
    int j0 = bbase[b], j1 = bbase[b + 1];
    for (int j = j0 + threadIdx.x; j < j1; j += 256) {
        uint4 e = bbuf[j];
        int d = (int)e.w;
        int slot = atomicAdd(&cursor[d], 1);
        csr[slot] = e;
    }
    __syncthreads();
    int n0 = b << 7, n1 = min(n0 + 128, N);
    uint4 sent = make_uint4(0xFFFF0000u, 0, 0, 0);
    for (int n = n0 + threadIdx.x; n < n1; n += 256) {
        int s1 = row_start[n + 1];
        for (int s = cursor[n]; s < s1; ++s) csr[s] = sent;
    }
}

// ---------------- p0 = x0 @ P0[0] (layer 0 only) ----------------
__global__ void k_p0(const float* __restrict__ x0, const float* __restrict__ P0l,
                     float* __restrict__ p0, int N) {
    int i = blockIdx.x * blockDim.x + threadIdx.x;
    if (i >= N * 16) return;
    int n = i >> 4, m = i & 15;
    float acc = 0.0f;
    #pragma unroll
    for (int c = 0; c < 16; ++c) acc += x0[n * 16 + c] * P0l[c * 16 + m];
    p0[i] = acc;
}

// ---------------- fused aggregation + node update; wave per node, 4 edge-slots x 16 ch ----------------
__launch_bounds__(256)
__global__ void k_aggupd(const int* __restrict__ row_start, const uint4* __restrict__ csr,
                         const uint2* __restrict__ tb2, const float* __restrict__ p0g,
                         const float* __restrict__ x0c, const float* __restrict__ x1c,
                         const float* __restrict__ x2c,
                         float* __restrict__ x0n, float* __restrict__ x1n, float* __restrict__ x2n,
                         float* __restrict__ p0out,
                         const float* __restrict__ Wsc, const float* __restrict__ Wa,
                         const float* __restrict__ W1m, const float* __restrict__ W2m,
                         const float* __restrict__ P0n,
                         int N, int ldx12, int wp0) {
    const float INVS = 0.17677669529663687f;  // 1/sqrt(32)
    const float K1  = 1.2909944487358056f;    // sqrt(15)/3
    const float S5H = 1.118033988749895f;     // sqrt(5)/2
    const float K2  = 0.6454972243679028f;    // sqrt(15)/2/3
    __shared__ float AGG[4][144];
    __shared__ float XIN[4][144];
    int tid = threadIdx.x;
    int wid = tid >> 6;
    int lane = tid & 63;
    int n = blockIdx.x * 4 + wid;
    int g = lane >> 4, c = lane & 15;
    float a0 = 0, a10 = 0, a11 = 0, a12 = 0, a20 = 0, a21 = 0, a22 = 0, a23 = 0, a24 = 0;
    float xr0 = 0, xr1 = 0, xr2 = 0, xr2b = 0;
    if (n < N) {
        if (lane < 16) xr0 = x0c[n * 16 + lane];
        if (ldx12) {
            if (lane < 48) xr1 = x1c[(size_t)n * 48 + lane];
            xr2 = x2c[(size_t)n * 80 + lane];
            if (lane < 16) xr2b = x2c[(size_t)n * 80 + 64 + lane];
        }
        int e0 = row_start[n], e1 = row_start[n + 1];
        if (e1 > e0) {
            int j0 = e0 + g;
            uint4 ca = csr[j0];
            uint4 cb = csr[j0 + 4];
            uint4 cc_ = csr[j0 + 8];
            float  pA = p0g[(ca.x & 0xffffu) * 16 + c];
            uint2  TA = tb2[(ca.x >> 20) * 16 + c];
            float2 uA = unp_h2(ca.y);
            float  zA = __uint_as_float(ca.z);
            #pragma unroll 2
            for (int j = j0; j < e1; j += 4) {
                uint4 nn = csr[j + 12];
                // issue loads for edge j+4 (stage B)
                float  pB = p0g[(cb.x & 0xffffu) * 16 + c];
                uint2  TB = tb2[(cb.x >> 20) * 16 + c];
                float2 uB = unp_h2(cb.y);
                float  zB = __uint_as_float(cb.z);
                // compute edge j (stage A; sentinel rows -> zero weights -> zero contribution)
                float ux = uA.x, uy = uA.y, uz = zA;
                float2 w01 = unp_h2(TA.x);
                float2 w2_ = unp_h2(TA.y);
                float sh20 = K1 * (ux * uy);
                float sh21 = K1 * (uy * uz);
                float sh22 = S5H * (uz * uz - 1.0f);
                float sh23 = K1 * (ux * uz);
                float sh24 = K2 * (ux * ux - uy * uy);
                a0 += w01.x * pA;
                float w1p = w01.y * pA, w2p = w2_.x * pA;
                a10 += w1p * ux; a11 += w1p * uy; a12 += w1p * uz;
                a20 += w2p * sh20; a21 += w2p * sh21; a22 += w2p * sh22;
                a23 += w2p * sh23; a24 += w2p * sh24;
                // rotate pipeline
                pA = pB; TA = TB; uA = uB; zA = zB;
                cb = cc_; cc_ = nn;
            }
        }
    }
    #pragma unroll
    for (int m = 16; m < 64; m <<= 1) {
        a0  += __shfl_xor(a0, m);
        a10 += __shfl_xor(a10, m); a11 += __shfl_xor(a11, m); a12 += __shfl_xor(a12, m);
        a20 += __shfl_xor(a20, m); a21 += __shfl_xor(a21, m); a22 += __shfl_xor(a22, m);
        a23 += __shfl_xor(a23, m); a24 += __shfl_xor(a24, m);
    }
    float* A = AGG[wid];
    if (lane < 16) {
        A[c] = a0 * INVS;
        A[16 + c * 3 + 0] = a10 * INVS; A[16 + c * 3 + 1] = a11 * INVS; A[16 + c * 3 + 2] = a12 * INVS;
        A[64 + c * 5 + 0] = a20 * INVS; A[64 + c * 5 + 1] = a21 * INVS; A[64 + c * 5 + 2] = a22 * INVS;
        A[64 + c * 5 + 3] = a23 * INVS; A[64 + c * 5 + 4] = a24 * INVS;
    }
    {
        float* X = XIN[wid];
        if (lane < 16) X[lane] = xr0;
        if (lane < 48) X[16 + lane] = xr1;
        X[64 + lane] = xr2;
        if (lane < 16) X[128 + lane] = xr2b;
    }
    __syncthreads();
    if (n >= N) return;
    const float* X = XIN[wid];
    float act = 0.0f;
    if (lane < 48) {
        float sj = 0.0f;
        #pragma unroll
        for (int cc = 0; cc < 16; ++cc)
            sj += X[cc] * Wsc[cc * 48 + lane] + A[cc] * Wa[cc * 48 + lane];
        float sg = sigmoidf_(sj);
        act = (lane < 16) ? sj * sg : sg;
    }
    if (lane < 16) x0n[n * 16 + lane] = act;
    // p0 for next layer: p0out[n][m] = sum_cc act[cc] * P0n[cc][m]
    if (wp0) {
        float pn = 0.0f;
        #pragma unroll
        for (int cc = 0; cc < 16; ++cc) pn += __shfl(act, cc) * P0n[cc * 16 + (lane & 15)];
        if (lane < 16) p0out[n * 16 + lane] = pn;
    }
    {
        int d = lane >> 4, m = lane & 15;
        float v = 0.0f;
        if (lane < 48) {
            if (ldx12) {
                #pragma unroll
                for (int cc = 0; cc < 16; ++cc) v += X[16 + cc * 3 + d] * W1m[cc * 16 + m];
            }
            v += A[16 + m * 3 + d];
        }
        float sg1 = __shfl(act, 16 + m);
        if (lane < 48) x1n[(size_t)n * 48 + m * 3 + d] = v * sg1;
    }
    #pragma unroll
    for (int ch = 0; ch < 2; ++ch) {
        int idx = ch * 64 + lane;
        int d = idx >> 4, m = idx & 15;
        bool on = idx < 80;
        float v = 0.0f;
        if (on) {
            if (ldx12) {
                #pragma unroll
                for (int cc = 0; cc < 16; ++cc) v += X[64 + cc * 5 + d] * W2m[cc * 16 + m];
            }
            v += A[64 + m * 5 + d];
        }
        float sg2 = __shfl(act, 32 + (m & 15));
        if (on) x2n[(size_t)n * 80 + m * 5 + d] = v * sg2;
    }
}

// ---------------- final reduction ----------------
__global__ void k_out1(const float* __restrict__ x0, const float* __restrict__ Wout,
                       float* __restrict__ partial, int N) {
    __shared__ float red[256];
    int tid = threadIdx.x;
    float s = 0.0f;
    for (int n = blockIdx.x * blockDim.x + tid; n < N; n += gridDim.x * blockDim.x) {
        float acc = 0.0f;
        #pragma unroll
        for (int cc = 0; cc < 16; ++cc) acc += x0[n * 16 + cc] * Wout[cc];
        s += acc;
    }
    red[tid] = s;
    __syncthreads();
    for (int off = 128; off > 0; off >>= 1) {
        if (tid < off) red[tid] += red[tid + off];
        __syncthreads();
    }
    if (tid == 0) partial[blockIdx.x] = red[0];
}

__global__ void k_out2(const float* __restrict__ partial, float* __restrict__ out,
                       int nb, float scale) {
    __shared__ float red[256];
    int tid = threadIdx.x;
    red[tid] = (tid < nb) ? partial[tid] : 0.0f;
    __syncthreads();
    for (int off = 128; off > 0; off >>= 1) {
        if (tid < off) red[tid] += red[tid + off];
        __syncthreads();
    }
    if (tid == 0) out[0] = red[0] * scale;
}

extern "C" void kernel_launch(void* const* d_in, const int* in_sizes, int n_in,
                              void* d_out, int out_size, void* d_ws, size_t ws_size,
                              hipStream_t stream) {
    const float* pos = (const float*)d_in[0];
    const float* x   = (const float*)d_in[1];
    const int* esrc  = (const int*)d_in[2];
    const int* edst  = (const int*)d_in[3];
    const float* mlp_w1 = (const float*)d_in[5];
    const float* mlp_b1 = (const float*)d_in[6];
    const float* mlp_w2 = (const float*)d_in[7];
    const float* P0  = (const float*)d_in[8];
    const float* Wsc = (const float*)d_in[9];
    const float* Wa  = (const float*)d_in[10];
    const float* W1m = (const float*)d_in[11];
    const float* W2m = (const float*)d_in[12];
    const float* Wout = (const float*)d_in[13];
    int N = in_sizes[0] / 3;
    int E = in_sizes[2];
    int cap = E + 8 * N + 64;
    int nbuck = (N + 127) >> 7;

    char* ws = (char*)d_ws;
    size_t off = 0;
    auto alloc = [&](size_t bytes) -> void* {
        void* p = ws + off;
        off += (bytes + 255) & ~(size_t)255;
        return p;
    };
    int*    cnt       = (int*)alloc((size_t)N * 4);
    int*    row_start = (int*)alloc((size_t)(N + 1) * 4);
    int*    cursor    = (int*)alloc((size_t)N * 4);
    int*    bsum      = (int*)alloc(256 * 4);
    int*    boff      = (int*)alloc(256 * 4);
    int*    bhist     = (int*)alloc(512 * 4);
    int*    bbase     = (int*)alloc(513 * 4);
    int*    bcursor   = (int*)alloc(512 * 4);
    uint4*  csr       = (uint4*)alloc((size_t)cap * 16);
    float*  wtab      = (float*)alloc((size_t)3 * TSZ2 * 48 * 4);
    uint2*  tb2       = (uint2*)alloc((size_t)3 * TSZ2 * 16 * 8);
    float*  p0A = (float*)alloc((size_t)65536 * 16 * 4);   // src is 16-bit
    float*  p0B = (float*)alloc((size_t)65536 * 16 * 4);
    float*  x0A = (float*)alloc((size_t)N * 16 * 4);
    float*  x0B = (float*)alloc((size_t)N * 16 * 4);
    float*  x1B = (float*)alloc((size_t)N * 48 * 4);
    float*  x2B = (float*)alloc((size_t)N * 80 * 4);
    // union region: bbuf (setup-only) aliases x1A + x2A (first written in layer 1)
    size_t x1Asz = ((size_t)N * 48 * 4 + 255) & ~(size_t)255;
    size_t unionSz = x1Asz + (size_t)N * 80 * 4;
    size_t bbufSz = (size_t)E * 16;
    char*  unionA = (char*)alloc(unionSz > bbufSz ? unionSz : bbufSz);
    float* x1A = (float*)unionA;
    float* x2A = (float*)(unionA + x1Asz);
    uint4* bbuf = (uint4*)unionA;
    float*  partial = (float*)alloc(256 * 4);

    int nbscan = (N + SCB - 1) / SCB;
    int nchunk = (E + CHK - 1) / CHK;

    hipMemsetAsync(cnt, 0, (size_t)N * 4, stream);
    hipMemsetAsync(bhist, 0, 512 * 4, stream);
    k_table<<<3 * (TSZ2 / 32), 256, 0, stream>>>(mlp_w1, mlp_b1, mlp_w2, wtab);
    k_pack<<<(3 * TSZ2 * 16 + 255) / 256, 256, 0, stream>>>(wtab, tb2);
    k_hist<<<nchunk, 256, 0, stream>>>(edst, cnt, bhist, E);
    k_scanA<<<nbscan, 256, 0, stream>>>(cnt, bsum, N);
    k_scanB<<<1, 256, 0, stream>>>(bsum, boff, nbscan);
    k_scanC<<<nbscan, 256, 0, stream>>>(cnt, boff, row_start, cursor, N);
    k_bscan<<<1, 512, 0, stream>>>(bhist, bbase, bcursor, nbuck, E);
    k_scat1<<<nchunk, 256, 0, stream>>>(pos, esrc, edst, bcursor, bbuf, E, nbuck);
    k_scat2<<<nbuck, 256, 0, stream>>>(bbuf, bbase, cursor, row_start, csr, N);
    k_p0<<<(N * 16 + 255) / 256, 256, 0, stream>>>(x, P0, p0A, N);

    float* x0bufs[2] = {x0A, x0B};
    float* x1bufs[2] = {x1A, x1B};
    float* x2bufs[2] = {x2A, x2B};
    float* p0bufs[2] = {p0A, p0B};
    for (int l = 0; l < 3; ++l) {
        const float* x0c = (l == 0) ? x : x0bufs[l & 1];
        const float* x1c = x1bufs[l & 1];
        const float* x2c = x2bufs[l & 1];
        float* x0n = x0bufs[(l & 1) ^ 1];
        float* x1n = x1bufs[(l & 1) ^ 1];
        float* x2n = x2bufs[(l & 1) ^ 1];
        const float* p0c = p0bufs[l & 1];
        float* p0n = p0bufs[(l & 1) ^ 1];
        const float* P0next = (l < 2) ? (P0 + (l + 1) * 256) : P0;
        k_aggupd<<<(N + 3) / 4, 256, 0, stream>>>(row_start, csr, tb2 + (size_t)l * TSZ2 * 16, p0c,
                                                  x0c, x1c, x2c, x0n, x1n, x2n, p0n,
                                                  Wsc + l * 768, Wa + l * 768,
                                                  W1m + l * 256, W2m + l * 256, P0next, N,
                                                  (l == 0) ? 0 : 1, (l < 2) ? 1 : 0);
    }
    float scale = (float)(1.0 / sqrt((double)N));
    k_out1<<<256, 256, 0, stream>>>(x0bufs[1], Wout, partial, N);
    k_out2<<<1, 256, 0, stream>>>(partial, (float*)d_out, 256, scale);
}

// Round 8
// 390.503 us; speedup vs baseline: 1.3760x; 1.0483x over previous
//
#include <hip/hip_runtime.h>
#include <hip/hip_fp16.h>
#include <math.h>

#define TSZ2 4096
#define RMAXF 2.0f
#define NBAS 10
#define HID 100
#define SCB 1024   // scan elements per block
#define CHK 4096   // edges per binning block

__device__ __forceinline__ float sigmoidf_(float z) { return 1.0f / (1.0f + __expf(-z)); }
__device__ __forceinline__ float2 unp_h2(unsigned u) {
    __half2 h = __builtin_bit_cast(__half2, u);
    return __half22float2(h);
}
__device__ __forceinline__ unsigned pk_h2(float a, float b) {
    return __builtin_bit_cast(unsigned, __floats2half2_rn(a, b));
}

// ---------------- radial table (fp32, [l][t][48]), 32 t-values per block ----------------
__global__ void k_table(const float* __restrict__ w1, const float* __restrict__ b1,
                        const float* __restrict__ w2, float* __restrict__ wtab) {
    int l = blockIdx.x >> 7;
    int t0 = (blockIdx.x & 127) * 32;
    __shared__ float emb[32][NBAS];
    __shared__ float h[32][HID];
    __shared__ float w2s[HID * 48];
    int tid = threadIdx.x;
    for (int i = tid; i < HID * 48; i += 256) w2s[i] = w2[l * HID * 48 + i];
    for (int i = tid; i < 32 * NBAS; i += 256) {
        int tt = i / NBAS, bi = i % NBAS;
        float r = (16.0f * (t0 + tt) + 7.5f) * (RMAXF / 65535.0f);
        float d = (r - (bi + 0.5f) * 0.2f) * 5.0f;
        emb[tt][bi] = (fabsf(d) < 1.0f) ? cosf(1.5707963267948966f * d) * 3.1622776601683795f : 0.0f;
    }
    __syncthreads();
    for (int i = tid; i < 32 * HID; i += 256) {
        int tt = i / HID, hh = i % HID;
        float z = b1[l * HID + hh];
        #pragma unroll
        for (int bi = 0; bi < NBAS; ++bi) z += emb[tt][bi] * w1[(l * NBAS + bi) * HID + hh];
        h[tt][hh] = z * sigmoidf_(z);
    }
    __syncthreads();
    for (int i = tid; i < 32 * 48; i += 256) {
        int tt = i / 48, j = i % 48;
        float o = 0.0f;
        for (int k = 0; k < HID; ++k) o += h[tt][k] * w2s[k * 48 + j];
        wtab[((size_t)l * TSZ2 + t0 + tt) * 48 + j] = o;
    }
}

// ---------------- pack table: [l][t][c] uint2 {h2(w0,w1), h2(w2,0)} ----------------
__global__ void k_pack(const float* __restrict__ wtab, uint2* __restrict__ tp) {
    int idx = blockIdx.x * blockDim.x + threadIdx.x;
    if (idx >= 3 * TSZ2 * 16) return;
    int c = idx & 15;
    int t = (idx >> 4) & (TSZ2 - 1);
    int l = idx >> 16;
    uint2 o = make_uint2(0, 0);
    if (t != TSZ2 - 1) {  // last row = sentinel zeros
        const float* wt = wtab + ((size_t)l * TSZ2 + t) * 48;
        o.x = pk_h2(wt[c], wt[16 + c]);
        o.y = pk_h2(wt[32 + c], 0.0f);
    }
    tp[idx] = o;
}

// ---------------- histogram: per-node (global atomics) + per-bucket (LDS-agg) ----------------
__global__ void k_hist(const int* __restrict__ edst, int* cnt, int* bhist, int E) {
    __shared__ int lb[512];
    int tid = threadIdx.x;
    for (int i = tid; i < 512; i += 256) lb[i] = 0;
    __syncthreads();
    int e0 = blockIdx.x * CHK;
    #pragma unroll
    for (int k = 0; k < CHK / 256; ++k) {
        int e = e0 + k * 256 + tid;
        if (e < E) {
            int d = edst[e];
            atomicAdd(&cnt[d], 1);
            atomicAdd(&lb[d >> 7], 1);
        }
    }
    __syncthreads();
    for (int i = tid; i < 512; i += 256) if (lb[i]) atomicAdd(&bhist[i], lb[i]);
}

// ---------------- bucket scan (1 block, 512 threads) ----------------
__global__ void k_bscan(const int* __restrict__ bhist, int* __restrict__ bbase,
                        int* __restrict__ bcursor, int nbuck, int E) {
    __shared__ int part[512];
    int t = threadIdx.x;
    part[t] = (t < nbuck) ? bhist[t] : 0;
    __syncthreads();
    for (int off = 1; off < 512; off <<= 1) {
        int v = (t >= off) ? part[t - off] : 0;
        __syncthreads();
        part[t] += v;
        __syncthreads();
    }
    int ex = (t == 0) ? 0 : part[t - 1];
    if (t < nbuck) { bbase[t] = ex; bcursor[t] = ex; }
    if (t == 0) bbase[nbuck] = E;
}

// ---------------- node-level scans (padded to 8) ----------------
__global__ void k_scanA(const int* __restrict__ cnt, int* __restrict__ bsum, int N) {
    __shared__ int red[256];
    int base = blockIdx.x * SCB;
    int t = threadIdx.x;
    int s = 0;
    #pragma unroll
    for (int k = 0; k < 4; ++k) {
        int i = base + k * 256 + t;
        if (i < N) s += (cnt[i] + 7) & ~7;
    }
    red[t] = s;
    __syncthreads();
    for (int off = 128; off > 0; off >>= 1) {
        if (t < off) red[t] += red[t + off];
        __syncthreads();
    }
    if (t == 0) bsum[blockIdx.x] = red[0];
}

__global__ void k_scanB(const int* __restrict__ bsum, int* __restrict__ boff, int nb) {
    __shared__ int part[256];
    int t = threadIdx.x;
    part[t] = (t < nb) ? bsum[t] : 0;
    __syncthreads();
    for (int off = 1; off < 256; off <<= 1) {
        int v = (t >= off) ? part[t - off] : 0;
        __syncthreads();
        part[t] += v;
        __syncthreads();
    }
    boff[t] = (t == 0) ? 0 : part[t - 1];
}

__global__ void k_scanC(const int* __restrict__ cnt, const int* __restrict__ boff,
                        int* __restrict__ row_start, int* __restrict__ cursor, int N) {
    __shared__ int part[256];
    int b = blockIdx.x, t = threadIdx.x;
    int base = b * SCB;
    int v[4];
    int s = 0;
    #pragma unroll
    for (int k = 0; k < 4; ++k) {
        int i = base + t * 4 + k;
        v[k] = (i < N) ? ((cnt[i] + 7) & ~7) : 0;
        s += v[k];
    }
    part[t] = s;
    __syncthreads();
    for (int off = 1; off < 256; off <<= 1) {
        int x = (t >= off) ? part[t - off] : 0;
        __syncthreads();
        part[t] += x;
        __syncthreads();
    }
    int run = boff[b] + ((t == 0) ? 0 : part[t - 1]);
    #pragma unroll
    for (int k = 0; k < 4; ++k) {
        int i = base + t * 4 + k;
        if (i < N) {
            row_start[i] = run; cursor[i] = run; run += v[k];
            if (i == N - 1) row_start[N] = run;
        }
    }
}

// ---------------- phase 1: bin edges into dst-buckets with geometry, burst writes ----------------
__global__ void k_scat1(const float* __restrict__ pos, const int* __restrict__ esrc,
                        const int* __restrict__ edst, int* __restrict__ bcursor,
                        uint4* __restrict__ bbuf, int E, int nbuck) {
    __shared__ int lcnt[512];
    __shared__ int base[512];
    int tid = threadIdx.x;
    for (int i = tid; i < 512; i += 256) lcnt[i] = 0;
    __syncthreads();
    int e0 = blockIdx.x * CHK;
    #pragma unroll
    for (int k = 0; k < CHK / 256; ++k) {
        int e = e0 + k * 256 + tid;
        if (e < E) atomicAdd(&lcnt[edst[e] >> 7], 1);
    }
    __syncthreads();
    for (int b = tid; b < nbuck; b += 256)
        base[b] = lcnt[b] ? atomicAdd(&bcursor[b], lcnt[b]) : 0;
    __syncthreads();
    #pragma unroll
    for (int k = 0; k < CHK / 256; ++k) {
        int e = e0 + k * 256 + tid;
        if (e >= E) continue;
        int s = esrc[e], d = edst[e];
        float vx = pos[s * 3 + 0] - pos[d * 3 + 0];
        float vy = pos[s * 3 + 1] - pos[d * 3 + 1];
        float vz = pos[s * 3 + 2] - pos[d * 3 + 2];
        float r = sqrtf(vx * vx + vy * vy + vz * vz);
        float kf = 1.7320508075688772f / (r + 1e-12f);   // sqrt(3)/r premult
        unsigned rtfix = (unsigned)fminf(r * (65535.0f / RMAXF) + 0.5f, 65535.0f);
        uint4 o;
        o.x = (unsigned)s | (rtfix << 16);
        o.y = pk_h2(vx * kf, vy * kf);
        o.z = __float_as_uint(vz * kf);
        o.w = (unsigned)d;
        int slot = atomicAdd(&base[d >> 7], 1);
        bbuf[slot] = o;
    }
}

// ---------------- phase 2: bucket -> exact CSR slot + sentinel padfill (fused) ----------------
__global__ void k_scat2(const uint4* __restrict__ bbuf, const int* __restrict__ bbase,
                        int* __restrict__ cursor, const int* __restrict__ row_start,
                        uint4* __restrict__ csr, int N) {
    int b = blockIdx.x;
    int j0 = bbase[b], j1 = bbase[b + 1];
    for (int j = j0 + threadIdx.x; j < j1; j += 256) {
        uint4 e = bbuf[j];
        int d = (int)e.w;
        int slot = atomicAdd(&cursor[d], 1);
        csr[slot] = e;
    }
    __syncthreads();
    int n0 = b << 7, n1 = min(n0 + 128, N);
    uint4 sent = make_uint4(0xFFFF0000u, 0, 0, 0);
    for (int n = n0 + threadIdx.x; n < n1; n += 256) {
        int s1 = row_start[n + 1];
        for (int s = cursor[n]; s < s1; ++s) csr[s] = sent;
    }
}

// ---------------- p0 = x0 @ P0[0] (layer 0 only) ----------------
__global__ void k_p0(const float* __restrict__ x0, const float* __restrict__ P0l,
                     float* __restrict__ p0, int N) {
    int i = blockIdx.x * blockDim.x + threadIdx.x;
    if (i >= N * 16) return;
    int n = i >> 4, m = i & 15;
    float acc = 0.0f;
    #pragma unroll
    for (int c = 0; c < 16; ++c) acc += x0[n * 16 + c] * P0l[c * 16 + m];
    p0[i] = acc;
}

// ---------------- fused aggregation + node update; wave per node, 4 edge-slots x 16 ch ----------------
__launch_bounds__(256)
__global__ void k_aggupd(const int* __restrict__ row_start, const uint4* __restrict__ csr,
                         const uint2* __restrict__ tb2, const float* __restrict__ p0g,
                         const float* __restrict__ x0c, const float* __restrict__ x1c,
                         const float* __restrict__ x2c,
                         float* __restrict__ x0n, float* __restrict__ x1n, float* __restrict__ x2n,
                         float* __restrict__ p0out,
                         const float* __restrict__ Wsc, const float* __restrict__ Wa,
                         const float* __restrict__ W1m, const float* __restrict__ W2m,
                         const float* __restrict__ P0n,
                         int N, int ldx12, int wp0) {
    const float INVS = 0.17677669529663687f;  // 1/sqrt(32)
    const float K1  = 1.2909944487358056f;    // sqrt(15)/3
    const float S5H = 1.118033988749895f;     // sqrt(5)/2
    const float K2  = 0.6454972243679028f;    // sqrt(15)/2/3
    __shared__ uint4 ROW[4][144];   // per-wave CSR row buffer (128 edges + overrun slack)
    __shared__ float AGG[4][144];
    __shared__ float XIN[4][144];
    int tid = threadIdx.x;
    int wid = tid >> 6;
    int lane = tid & 63;
    int n = blockIdx.x * 4 + wid;
    int g = lane >> 4, c = lane & 15;
    float a0 = 0, a10 = 0, a11 = 0, a12 = 0, a20 = 0, a21 = 0, a22 = 0, a23 = 0, a24 = 0;
    float xr0 = 0, xr1 = 0, xr2 = 0, xr2b = 0;
    auto EDGE = [&](uint4 cv, float pv, uint2 Tv) {
        float2 uxy = unp_h2(cv.y);
        float ux = uxy.x, uy = uxy.y, uz = __uint_as_float(cv.z);
        float2 w01 = unp_h2(Tv.x);
        float2 w2_ = unp_h2(Tv.y);
        float sh20 = K1 * (ux * uy);
        float sh21 = K1 * (uy * uz);
        float sh22 = S5H * (uz * uz - 1.0f);
        float sh23 = K1 * (ux * uz);
        float sh24 = K2 * (ux * ux - uy * uy);
        a0 += w01.x * pv;
        float w1p = w01.y * pv, w2p = w2_.x * pv;
        a10 += w1p * ux; a11 += w1p * uy; a12 += w1p * uz;
        a20 += w2p * sh20; a21 += w2p * sh21; a22 += w2p * sh22;
        a23 += w2p * sh23; a24 += w2p * sh24;
    };
    if (n < N) {
        int e0 = row_start[n], e1 = row_start[n + 1];
        int plen = e1 - e0;
        if (lane < 16) xr0 = x0c[n * 16 + lane];
        if (ldx12) {
            if (lane < 48) xr1 = x1c[(size_t)n * 48 + lane];
            xr2 = x2c[(size_t)n * 80 + lane];
            if (lane < 16) xr2b = x2c[(size_t)n * 80 + 64 + lane];
        }
        if (plen > 0) {
            // ---- stage CSR row into LDS via async DMA (lane-contiguous dest) ----
            __builtin_amdgcn_global_load_lds(
                (const __attribute__((address_space(1))) void*)(csr + e0 + lane),
                (__attribute__((address_space(3))) void*)(&ROW[wid][0]), 16, 0, 0);
            if (plen > 64)
                __builtin_amdgcn_global_load_lds(
                    (const __attribute__((address_space(1))) void*)(csr + e0 + 64 + lane),
                    (__attribute__((address_space(3))) void*)(&ROW[wid][64]), 16, 0, 0);
            asm volatile("s_waitcnt vmcnt(0)" ::: "memory");
            const uint4* RB = ROW[wid];
            int L = (plen + 3) >> 2;         // 4-edge groups (padded rows: even)
            int Lm = L < 32 ? L : 32;        // LDS covers 128 edges
            // ---- 4-deep LDS window + 2-deep global (p0/tb2) pipeline ----
            uint4 c0 = RB[g];
            uint4 c1 = RB[4 + g];
            uint4 c2 = RB[8 + g];
            uint4 c3 = RB[12 + g];
            float p0v = p0g[(c0.x & 0xffffu) * 16 + c];
            uint2 T0  = tb2[((c0.x >> 16) & 0xfff0u) | c];
            float p1v = p0g[(c1.x & 0xffffu) * 16 + c];
            uint2 T1  = tb2[((c1.x >> 16) & 0xfff0u) | c];
            #pragma unroll 2
            for (int k = 0; k < Lm; ++k) {
                uint4 c4 = RB[(k + 4) * 4 + g];
                float p2v = p0g[(c2.x & 0xffffu) * 16 + c];
                uint2 T2  = tb2[((c2.x >> 16) & 0xfff0u) | c];
                EDGE(c0, p0v, T0);
                c0 = c1; c1 = c2; c2 = c3; c3 = c4;
                p0v = p1v; T0 = T1;
                p1v = p2v; T1 = T2;
            }
            // rare fallback: rows longer than 128 edges
            if (plen > 128) {
                for (int j = e0 + 128 + g; j < e1; j += 4) {
                    uint4 cx = csr[j];
                    float pv = p0g[(cx.x & 0xffffu) * 16 + c];
                    uint2 Tx = tb2[((cx.x >> 16) & 0xfff0u) | c];
                    EDGE(cx, pv, Tx);
                }
            }
        }
    }
    #pragma unroll
    for (int m = 16; m < 64; m <<= 1) {
        a0  += __shfl_xor(a0, m);
        a10 += __shfl_xor(a10, m); a11 += __shfl_xor(a11, m); a12 += __shfl_xor(a12, m);
        a20 += __shfl_xor(a20, m); a21 += __shfl_xor(a21, m); a22 += __shfl_xor(a22, m);
        a23 += __shfl_xor(a23, m); a24 += __shfl_xor(a24, m);
    }
    float* A = AGG[wid];
    if (lane < 16) {
        A[c] = a0 * INVS;
        A[16 + c * 3 + 0] = a10 * INVS; A[16 + c * 3 + 1] = a11 * INVS; A[16 + c * 3 + 2] = a12 * INVS;
        A[64 + c * 5 + 0] = a20 * INVS; A[64 + c * 5 + 1] = a21 * INVS; A[64 + c * 5 + 2] = a22 * INVS;
        A[64 + c * 5 + 3] = a23 * INVS; A[64 + c * 5 + 4] = a24 * INVS;
    }
    {
        float* X = XIN[wid];
        if (lane < 16) X[lane] = xr0;
        if (lane < 48) X[16 + lane] = xr1;
        X[64 + lane] = xr2;
        if (lane < 16) X[128 + lane] = xr2b;
    }
    __syncthreads();
    if (n >= N) return;
    const float* X = XIN[wid];
    float act = 0.0f;
    if (lane < 48) {
        float sj = 0.0f;
        #pragma unroll
        for (int cc = 0; cc < 16; ++cc)
            sj += X[cc] * Wsc[cc * 48 + lane] + A[cc] * Wa[cc * 48 + lane];
        float sg = sigmoidf_(sj);
        act = (lane < 16) ? sj * sg : sg;
    }
    if (lane < 16) x0n[n * 16 + lane] = act;
    // p0 for next layer: p0out[n][m] = sum_cc act[cc] * P0n[cc][m]
    if (wp0) {
        float pn = 0.0f;
        #pragma unroll
        for (int cc = 0; cc < 16; ++cc) pn += __shfl(act, cc) * P0n[cc * 16 + (lane & 15)];
        if (lane < 16) p0out[n * 16 + lane] = pn;
    }
    {
        int d = lane >> 4, m = lane & 15;
        float v = 0.0f;
        if (lane < 48) {
            if (ldx12) {
                #pragma unroll
                for (int cc = 0; cc < 16; ++cc) v += X[16 + cc * 3 + d] * W1m[cc * 16 + m];
            }
            v += A[16 + m * 3 + d];
        }
        float sg1 = __shfl(act, 16 + m);
        if (lane < 48) x1n[(size_t)n * 48 + m * 3 + d] = v * sg1;
    }
    #pragma unroll
    for (int ch = 0; ch < 2; ++ch) {
        int idx = ch * 64 + lane;
        int d = idx >> 4, m = idx & 15;
        bool on = idx < 80;
        float v = 0.0f;
        if (on) {
            if (ldx12) {
                #pragma unroll
                for (int cc = 0; cc < 16; ++cc) v += X[64 + cc * 5 + d] * W2m[cc * 16 + m];
            }
            v += A[64 + m * 5 + d];
        }
        float sg2 = __shfl(act, 32 + (m & 15));
        if (on) x2n[(size_t)n * 80 + m * 5 + d] = v * sg2;
    }
}

// ---------------- final reduction ----------------
__global__ void k_out1(const float* __restrict__ x0, const float* __restrict__ Wout,
                       float* __restrict__ partial, int N) {
    __shared__ float red[256];
    int tid = threadIdx.x;
    float s = 0.0f;
    for (int n = blockIdx.x * blockDim.x + tid; n < N; n += gridDim.x * blockDim.x) {
        float acc = 0.0f;
        #pragma unroll
        for (int cc = 0; cc < 16; ++cc) acc += x0[n * 16 + cc] * Wout[cc];
        s += acc;
    }
    red[tid] = s;
    __syncthreads();
    for (int off = 128; off > 0; off >>= 1) {
        if (tid < off) red[tid] += red[tid + off];
        __syncthreads();
    }
    if (tid == 0) partial[blockIdx.x] = red[0];
}

__global__ void k_out2(const float* __restrict__ partial, float* __restrict__ out,
                       int nb, float scale) {
    __shared__ float red[256];
    int tid = threadIdx.x;
    red[tid] = (tid < nb) ? partial[tid] : 0.0f;
    __syncthreads();
    for (int off = 128; off > 0; off >>= 1) {
        if (tid < off) red[tid] += red[tid + off];
        __syncthreads();
    }
    if (tid == 0) out[0] = red[0] * scale;
}

extern "C" void kernel_launch(void* const* d_in, const int* in_sizes, int n_in,
                              void* d_out, int out_size, void* d_ws, size_t ws_size,
                              hipStream_t stream) {
    const float* pos = (const float*)d_in[0];
    const float* x   = (const float*)d_in[1];
    const int* esrc  = (const int*)d_in[2];
    const int* edst  = (const int*)d_in[3];
    const float* mlp_w1 = (const float*)d_in[5];
    const float* mlp_b1 = (const float*)d_in[6];
    const float* mlp_w2 = (const float*)d_in[7];
    const float* P0  = (const float*)d_in[8];
    const float* Wsc = (const float*)d_in[9];
    const float* Wa  = (const float*)d_in[10];
    const float* W1m = (const float*)d_in[11];
    const float* W2m = (const float*)d_in[12];
    const float* Wout = (const float*)d_in[13];
    int N = in_sizes[0] / 3;
    int E = in_sizes[2];
    int cap = E + 8 * N + 256;
    int nbuck = (N + 127) >> 7;

    char* ws = (char*)d_ws;
    size_t off = 0;
    auto alloc = [&](size_t bytes) -> void* {
        void* p = ws + off;
        off += (bytes + 255) & ~(size_t)255;
        return p;
    };
    int*    cnt       = (int*)alloc((size_t)N * 4);
    int*    row_start = (int*)alloc((size_t)(N + 1) * 4);
    int*    cursor    = (int*)alloc((size_t)N * 4);
    int*    bsum      = (int*)alloc(256 * 4);
    int*    boff      = (int*)alloc(256 * 4);
    int*    bhist     = (int*)alloc(512 * 4);
    int*    bbase     = (int*)alloc(513 * 4);
    int*    bcursor   = (int*)alloc(512 * 4);
    uint4*  csr       = (uint4*)alloc((size_t)cap * 16);
    float*  wtab      = (float*)alloc((size_t)3 * TSZ2 * 48 * 4);
    uint2*  tb2       = (uint2*)alloc((size_t)3 * TSZ2 * 16 * 8);
    float*  p0A = (float*)alloc((size_t)65536 * 16 * 4);   // src is 16-bit
    float*  p0B = (float*)alloc((size_t)65536 * 16 * 4);
    float*  x0A = (float*)alloc((size_t)N * 16 * 4);
    float*  x0B = (float*)alloc((size_t)N * 16 * 4);
    float*  x1B = (float*)alloc((size_t)N * 48 * 4);
    float*  x2B = (float*)alloc((size_t)N * 80 * 4);
    // union region: bbuf (setup-only) aliases x1A + x2A (first written in layer 1)
    size_t x1Asz = ((size_t)N * 48 * 4 + 255) & ~(size_t)255;
    size_t unionSz = x1Asz + (size_t)N * 80 * 4;
    size_t bbufSz = (size_t)E * 16;
    char*  unionA = (char*)alloc(unionSz > bbufSz ? unionSz : bbufSz);
    float* x1A = (float*)unionA;
    float* x2A = (float*)(unionA + x1Asz);
    uint4* bbuf = (uint4*)unionA;
    float*  partial = (float*)alloc(256 * 4);

    int nbscan = (N + SCB - 1) / SCB;
    int nchunk = (E + CHK - 1) / CHK;

    hipMemsetAsync(cnt, 0, (size_t)N * 4, stream);
    hipMemsetAsync(bhist, 0, 512 * 4, stream);
    k_table<<<3 * (TSZ2 / 32), 256, 0, stream>>>(mlp_w1, mlp_b1, mlp_w2, wtab);
    k_pack<<<(3 * TSZ2 * 16 + 255) / 256, 256, 0, stream>>>(wtab, tb2);
    k_hist<<<nchunk, 256, 0, stream>>>(edst, cnt, bhist, E);
    k_scanA<<<nbscan, 256, 0, stream>>>(cnt, bsum, N);
    k_scanB<<<1, 256, 0, stream>>>(bsum, boff, nbscan);
    k_scanC<<<nbscan, 256, 0, stream>>>(cnt, boff, row_start, cursor, N);
    k_bscan<<<1, 512, 0, stream>>>(bhist, bbase, bcursor, nbuck, E);
    k_scat1<<<nchunk, 256, 0, stream>>>(pos, esrc, edst, bcursor, bbuf, E, nbuck);
    k_scat2<<<nbuck, 256, 0, stream>>>(bbuf, bbase, cursor, row_start, csr, N);
    k_p0<<<(N * 16 + 255) / 256, 256, 0, stream>>>(x, P0, p0A, N);

    float* x0bufs[2] = {x0A, x0B};
    float* x1bufs[2] = {x1A, x1B};
    float* x2bufs[2] = {x2A, x2B};
    float* p0bufs[2] = {p0A, p0B};
    for (int l = 0; l < 3; ++l) {
        const float* x0c = (l == 0) ? x : x0bufs[l & 1];
        const float* x1c = x1bufs[l & 1];
        const float* x2c = x2bufs[l & 1];
        float* x0n = x0bufs[(l & 1) ^ 1];
        float* x1n = x1bufs[(l & 1) ^ 1];
        float* x2n = x2bufs[(l & 1) ^ 1];
        const float* p0c = p0bufs[l & 1];
        float* p0n = p0bufs[(l & 1) ^ 1];
        const float* P0next = (l < 2) ? (P0 + (l + 1) * 256) : P0;
        k_aggupd<<<(N + 3) / 4, 256, 0, stream>>>(row_start, csr, tb2 + (size_t)l * TSZ2 * 16, p0c,
                                                  x0c, x1c, x2c, x0n, x1n, x2n, p0n,
                                                  Wsc + l * 768, Wa + l * 768,
                                                  W1m + l * 256, W2m + l * 256, P0next, N,
                                                  (l == 0) ? 0 : 1, (l < 2) ? 1 : 0);
    }
    float scale = (float)(1.0 / sqrt((double)N));
    k_out1<<<256, 256, 0, stream>>>(x0bufs[1], Wout, partial, N);
    k_out2<<<1, 256, 0, stream>>>(partial, (float*)d_out, 256, scale);
}